// Round 7
// baseline (239.551 us; speedup 1.0000x reference)
//
#include <hip/hip_runtime.h>

typedef short s16x4 __attribute__((ext_vector_type(4)));
typedef short s16x8 __attribute__((ext_vector_type(8)));
typedef float f32x2 __attribute__((ext_vector_type(2)));
typedef float f32x16 __attribute__((ext_vector_type(16)));
typedef unsigned int u32x2 __attribute__((ext_vector_type(2)));
typedef unsigned int u32x4 __attribute__((ext_vector_type(4)));

#define HT_STRIDE 72  // bf16 row stride: 144 B = 9*16 -> 16B-aligned b128 rows

__device__ __forceinline__ unsigned short f2bf(float f) {
    unsigned int u = __float_as_uint(f);
    u += 0x7fffu + ((u >> 16) & 1u);
    return (unsigned short)(u >> 16);
}
__device__ __forceinline__ unsigned int pk2bf_rne(float lo, float hi) {
    unsigned int a = __float_as_uint(lo);
    a += 0x7fffu + ((a >> 16) & 1u);
    unsigned int b = __float_as_uint(hi);
    b += 0x7fffu + ((b >> 16) & 1u);
    return (a >> 16) | (b & 0xffff0000u);
}

// Inline-asm 16B global load: issue point pinned in program order (memory
// clobber + sched_barrier fences) — regalloc cannot collapse the distance.
#define GLOADX4(dst, base, OFF)                                       \
    asm volatile("global_load_dwordx4 %0, %1, off offset:" OFF        \
                 : "=&v"(dst) : "v"(base) : "memory")

// Factorization: T_l[(o,j),d] = sum_i W_l[o, i*64+j] * x[i,d]  (GEMM, K=i=64)
// A-frag prepack for 32x32x16: rows m = j_local (j = jt*32 + m), k = i.
// Wp frag index F = ((l*64+o)*2+jt)*4+ks ; value[lane][t] =
//   bf16( W_l[o][ (16*ks + 8*(lane>>5) + t)*64 + jt*32 + (lane&31) ] )
__global__ __launch_bounds__(256) void prepack_kernel(const float* __restrict__ W1,
                                                      const float* __restrict__ W2,
                                                      unsigned short* __restrict__ Wp) {
    int tid = blockIdx.x * 256 + threadIdx.x; // 0..65535, one 16B frag slice each
    int lane = tid & 63;
    int ks = (tid >> 6) & 3;
    int jt = (tid >> 8) & 1;
    int o = (tid >> 9) & 63;
    int l = tid >> 15;
    int q2 = lane >> 5;
    int n31 = lane & 31;
    const float* W = l ? W2 : W1;
    const float* base = W + o * 4096 + jt * 32 + n31;
    int i0 = 16 * ks + 8 * q2;
    float v[8];
#pragma unroll
    for (int t = 0; t < 8; ++t) v[t] = base[(i0 + t) * 64];
    u32x4 pv;
    pv[0] = pk2bf_rne(v[0], v[1]);
    pv[1] = pk2bf_rne(v[2], v[3]);
    pv[2] = pk2bf_rne(v[4], v[5]);
    pv[3] = pk2bf_rne(v[6], v[7]);
    ((u32x4*)Wp)[tid] = pv;
}

// Block = 1 batch elem, 4 waves, wave w owns o ≡ w (mod 4), both d-halves.
// Rounds 0-6 post-mortem: period pinned at ~1378 cyc/it regardless of prefetch
// depth (r6: enforced depth-3, null), VALU count (r2/r3: null), occupancy
// attempts (r1/r2: acc-register tax pins us at 2 waves/SIMD). The remaining
// serial structure: MFMA chain -> stall for results -> consume -> next MFMA.
// THIS version: DEFERRED CONSUME. Two accumulator generations (A/B, literal-
// indexed). Iteration it issues MFMA(it) into gen[it&1] FIRST, then consumes
// gen[(it-1)&1] (results guaranteed complete) on the VALU while the matrix
// pipe works in the background. Epilogue consumes it=31.
__global__ __launch_bounds__(256, 2) void cin_kernel(const float* __restrict__ x,
                                                     const unsigned short* __restrict__ Wp,
                                                     const float* __restrict__ b1,
                                                     const float* __restrict__ b2,
                                                     const float* __restrict__ Wfc,
                                                     const float* __restrict__ bfc,
                                                     float* __restrict__ out) {
    // sH[l][d*72 + j]: layer-l j-factor source (l=0: x, l=1: h1), bf16 transposed
    __shared__ __align__(16) unsigned short sH[2][64 * HT_STRIDE]; // 18.4 KB
    __shared__ float sBias[128], sWfc[128], sRed[4];

    const int tid = threadIdx.x;
    const int w = tid >> 6;
    const int lane = tid & 63;
    const int q2 = lane >> 5;
    const int n31 = lane & 31;
    const int oh = w; // o ≡ oh (mod 4)
    const int bb = blockIdx.x;
    const char* WpB = (const char*)Wp;

    // ---- stage x: coalesced float4 reads -> transposed bf16 LDS ----
    {
        const float4* xb4 = (const float4*)(x + bb * 4096);
#pragma unroll
        for (int rr = 0; rr < 4; ++rr) {
            int e4 = rr * 256 + tid;
            float4 v = xb4[e4];
            int e = e4 << 2;
            int f = e >> 6;     // field index (i / j)
            int d0 = e & 63;    // d-index
            sH[0][(d0 + 0) * HT_STRIDE + f] = f2bf(v.x);
            sH[0][(d0 + 1) * HT_STRIDE + f] = f2bf(v.y);
            sH[0][(d0 + 2) * HT_STRIDE + f] = f2bf(v.z);
            sH[0][(d0 + 3) * HT_STRIDE + f] = f2bf(v.w);
        }
    }
    if (tid < 128) {
        sBias[tid] = (tid < 64) ? b1[tid] : b2[tid - 64];
        sWfc[tid] = Wfc[tid];
    }
    __syncthreads();

    const f32x16 zz = {};
    float contrib = 0.0f;

    // ---- A-frag ring: 4 slots x 4 frags, asm-loaded (64 VGPR, really live) --
    s16x8 Ar[4][4];

    // ---- prologue: issue groups 0,1,2 (l=0, it=0..2) into slots 0,1,2 ----
#pragma unroll
    for (int g0 = 0; g0 < 3; ++g0) {
        const int F = (8 * (g0 >> 1) + 2 * oh + (g0 & 1)) * 4;
        const char* gp = WpB + (size_t)F * 1024 + lane * 16;
        GLOADX4(Ar[g0][0], gp, "0");
        GLOADX4(Ar[g0][1], gp, "1024");
        GLOADX4(Ar[g0][2], gp, "2048");
        GLOADX4(Ar[g0][3], gp, "3072");
    }
    __builtin_amdgcn_sched_barrier(0);

    // ---- MFMA B-frags: B[k=i][n=d] = x[i,d] — fixed for BOTH layers ----
    s16x8 bfr[2][4]; // [nt][ks]
#pragma unroll
    for (int nt = 0; nt < 2; ++nt) {
        const int d = nt * 32 + n31;
#pragma unroll
        for (int ks = 0; ks < 4; ++ks)
            bfr[nt][ks] = *(const s16x8*)&sH[0][d * HT_STRIDE + 16 * ks + 8 * q2];
    }

// consume one n-tile: weighted column-sum over the tile's 32 j-rows.
// cwp holds bf16 PAIRS; unpack = shift/mask (bf16 -> f32 is <<16).
// NT/JT are literals; O is a uniform runtime value.
#define CONSUME(NT, ACC, JT, O)                                                   \
    {                                                                             \
        const f32x2* a2 = (const f32x2*)&(ACC);                                   \
        f32x2 s0 = {0.0f, 0.0f}, s1 = {0.0f, 0.0f};                               \
        _Pragma("unroll") for (int m = 0; m < 4; ++m) {                           \
            unsigned int qlo = cwp[NT][JT][m][0];                                 \
            unsigned int qhi = cwp[NT][JT][m][1];                                 \
            f32x2 c0 = {__uint_as_float(qlo << 16),                               \
                        __uint_as_float(qlo & 0xffff0000u)};                      \
            f32x2 c1 = {__uint_as_float(qhi << 16),                               \
                        __uint_as_float(qhi & 0xffff0000u)};                      \
            s0 += a2[2 * m] * c0;                                                 \
            s1 += a2[2 * m + 1] * c1;                                             \
        }                                                                         \
        f32x2 s = s0 + s1;                                                        \
        if ((JT) == 0) {                                                          \
            hp[NT] = s;                                                           \
        } else {                                                                  \
            f32x2 t2 = hp[NT] + s;                                                \
            float hsum = t2.x + t2.y;                                             \
            hsum += __shfl_xor(hsum, 32, 64); /* partner q2-half rows */          \
            float v = fmaxf(hsum + sBias[l * 64 + (O)], 0.0f);                    \
            contrib += v * sWfc[l * 64 + (O)];                                    \
            if (l == 0) /* h1 handoff (both q2 halves write identical bits) */    \
                sH[1][((NT) * 32 + n31) * HT_STRIDE + (O)] = f2bf(v);             \
        }                                                                         \
    }

// 8-MFMA burst into CUR generation, slot S (literal)
#define MFMA8(S, C0, C1)                                                          \
    C0 = __builtin_amdgcn_mfma_f32_32x32x16_bf16(Ar[S][0], bfr[0][0], zz, 0, 0, 0); \
    C1 = __builtin_amdgcn_mfma_f32_32x32x16_bf16(Ar[S][0], bfr[1][0], zz, 0, 0, 0); \
    C0 = __builtin_amdgcn_mfma_f32_32x32x16_bf16(Ar[S][1], bfr[0][1], C0, 0, 0, 0); \
    C1 = __builtin_amdgcn_mfma_f32_32x32x16_bf16(Ar[S][1], bfr[1][1], C1, 0, 0, 0); \
    C0 = __builtin_amdgcn_mfma_f32_32x32x16_bf16(Ar[S][2], bfr[0][2], C0, 0, 0, 0); \
    C1 = __builtin_amdgcn_mfma_f32_32x32x16_bf16(Ar[S][2], bfr[1][2], C1, 0, 0, 0); \
    C0 = __builtin_amdgcn_mfma_f32_32x32x16_bf16(Ar[S][3], bfr[0][3], C0, 0, 0, 0); \
    C1 = __builtin_amdgcn_mfma_f32_32x32x16_bf16(Ar[S][3], bfr[1][3], C1, 0, 0, 0)

// One pipelined iteration. K = 0..3 literal (itb multiple of 4):
// slot = K, cur gen = K&1, prev it p = itb+K-1 (odd/even -> gen/jt literal).
#define PITER(K, C0, C1, P0, P1, PGUARD)                                          \
    {                                                                             \
        const int it_ = itb + (K);                                                \
        const int g = l * 32 + it_;                                               \
        if (g < 61) { /* prefetch group g+3 into slot (K+3)&3 */                  \
            const int gn = g + 3;                                                 \
            const int ln = gn >> 5, itn = gn & 31;                                \
            const int Fn = (ln * 128 + 8 * (itn >> 1) + 2 * oh + (itn & 1)) * 4;  \
            const char* gp = WpB + (size_t)Fn * 1024 + lane * 16;                 \
            GLOADX4(Ar[((K) + 3) & 3][0], gp, "0");                               \
            GLOADX4(Ar[((K) + 3) & 3][1], gp, "1024");                            \
            GLOADX4(Ar[((K) + 3) & 3][2], gp, "2048");                            \
            GLOADX4(Ar[((K) + 3) & 3][3], gp, "3072");                            \
        }                                                                         \
        __builtin_amdgcn_sched_barrier(0);                                        \
        if (g < 61) {                                                             \
            asm volatile("s_waitcnt vmcnt(12)" ::: "memory");                     \
        } else if (g == 61) {                                                     \
            asm volatile("s_waitcnt vmcnt(8)" ::: "memory");                      \
        } else if (g == 62) {                                                     \
            asm volatile("s_waitcnt vmcnt(4)" ::: "memory");                      \
        } else {                                                                  \
            asm volatile("s_waitcnt vmcnt(0)" ::: "memory");                      \
        }                                                                         \
        __builtin_amdgcn_sched_barrier(0);                                        \
        MFMA8((K) & 3, C0, C1); /* issue first; results needed next it */         \
        __builtin_amdgcn_sched_barrier(0); /* consume stays AFTER the burst */    \
        if (PGUARD) { /* consume prev it (results complete) */                    \
            const int po = 4 * ((it_ - 1) >> 1) + oh;                             \
            CONSUME(0, P0, ((K) + 1) & 1, po);                                    \
            CONSUME(1, P1, ((K) + 1) & 1, po);                                    \
        }                                                                         \
    }

    f32x16 aA0 = zz, aA1 = zz, aB0 = zz, aB1 = zz;

    for (int l = 0; l < 2; ++l) {
        if (l) __syncthreads(); // h1 writes complete (counted vmcnt waits stay
                                // self-sufficient across the barrier)

        // ---- per-layer consume weights (j-factor), PACKED bf16 pairs ----
        const unsigned short* hsrc = sH[l];
        u32x2 cwp[2][2][4]; // [nt][jt][m] = h[j= jt*32+4*q2+8*m+(0..3), d] pairs
#pragma unroll
        for (int nt = 0; nt < 2; ++nt) {
            const int d = nt * 32 + n31;
#pragma unroll
            for (int jt = 0; jt < 2; ++jt)
#pragma unroll
                for (int m = 0; m < 4; ++m)
                    cwp[nt][jt][m] =
                        *(const u32x2*)&hsrc[d * HT_STRIDE + jt * 32 + 4 * q2 + 8 * m];
        }

        f32x2 hp[2];

        for (int itb = 0; itb < 32; itb += 4) { // manual 4x unroll: literal K
            PITER(0, aA0, aA1, aB0, aB1, (itb > 0));
            PITER(1, aB0, aB1, aA0, aA1, 1);
            PITER(2, aA0, aA1, aB0, aB1, 1);
            PITER(3, aB0, aB1, aA0, aA1, 1);
        }
        // epilogue: consume it=31 (odd -> gen B, jt=1, o = 60+oh)
        CONSUME(0, aB0, 1, 60 + oh);
        CONSUME(1, aB1, 1, 60 + oh);
    }
#undef PITER
#undef MFMA8
#undef CONSUME

    // each (o,d) accumulated by both q2 halves -> halve at the end
    contrib *= 0.5f;
#pragma unroll
    for (int off = 32; off > 0; off >>= 1)
        contrib += __shfl_down(contrib, off, 64);
    if (lane == 0) sRed[w] = contrib;
    __syncthreads();
    if (tid == 0)
        out[bb] = (sRed[0] + sRed[1]) + (sRed[2] + sRed[3]) + bfc[0];
}

extern "C" void kernel_launch(void* const* d_in, const int* in_sizes, int n_in,
                              void* d_out, int out_size, void* d_ws, size_t ws_size,
                              hipStream_t stream) {
    const float* x = (const float*)d_in[0];
    const float* W1 = (const float*)d_in[1];
    const float* b1 = (const float*)d_in[2];
    const float* W2 = (const float*)d_in[3];
    const float* b2 = (const float*)d_in[4];
    const float* Wfc = (const float*)d_in[5];
    const float* bfc = (const float*)d_in[6];
    float* out = (float*)d_out;

    unsigned short* Wp = (unsigned short*)d_ws; // 524288 bf16 = 1 MB prepacked W'

    prepack_kernel<<<256, 256, 0, stream>>>(W1, W2, Wp);
    cin_kernel<<<1024, 256, 0, stream>>>(x, Wp, b1, b2, Wfc, bfc, out);
}

// Round 8
// 165.995 us; speedup vs baseline: 1.4431x; 1.4431x over previous
//
#include <hip/hip_runtime.h>

typedef short s16x4 __attribute__((ext_vector_type(4)));
typedef short s16x8 __attribute__((ext_vector_type(8)));
typedef float f32x2 __attribute__((ext_vector_type(2)));
typedef float f32x16 __attribute__((ext_vector_type(16)));
typedef unsigned int u32x2 __attribute__((ext_vector_type(2)));
typedef unsigned int u32x4 __attribute__((ext_vector_type(4)));

__device__ __forceinline__ unsigned short f2bf(float f) {
    unsigned int u = __float_as_uint(f);
    u += 0x7fffu + ((u >> 16) & 1u);
    return (unsigned short)(u >> 16);
}
__device__ __forceinline__ float bf2f(unsigned short h) {
    return __uint_as_float(((unsigned int)h) << 16);
}
__device__ __forceinline__ unsigned int pk2bf_rne(float lo, float hi) {
    unsigned int a = __float_as_uint(lo);
    a += 0x7fffu + ((a >> 16) & 1u);
    unsigned int b = __float_as_uint(hi);
    b += 0x7fffu + ((b >> 16) & 1u);
    return (a >> 16) | (b & 0xffff0000u);
}

// Inline-asm 16B global load: issue point pinned in program order.
#define GLOADX4(dst, base, OFF)                                       \
    asm volatile("global_load_dwordx4 %0, %1, off offset:" OFF        \
                 : "=&v"(dst) : "v"(base) : "memory")

// NEW FORMULATION (r8): h_next[o,d] = relu(b[o] + sum_k W[o,k]*y[k,d]),
// k = i*64+j, y[k,d] = x[i,d]*h_l[j,d]. A straight GEMM: the j-reduction that
// was a serial VALU consume in r0-r7 is now inside the MFMA K-dim. Accumulator
// is touched only at the layer epilogue -> no per-iteration MFMA->VALU
// round-trip on the critical path (the wall of rounds 0-7).
//
// Prepack for 32x32x16 A-operand: group G = ((l*2+wr)*64 + c)*4 + s (wr =
// o-half, c = K-chunk of 64, s = k-step of 16); value[lane][t] =
//   bf16( W_l[o = wr*32 + (lane&31)][ c*64 + s*16 + 8*(lane>>5) + t ] )
// Bit layout of G*64+lane == tid exactly.
__global__ __launch_bounds__(256) void prepack_kernel(const float* __restrict__ W1,
                                                      const float* __restrict__ W2,
                                                      unsigned short* __restrict__ Wp) {
    int tid = blockIdx.x * 256 + threadIdx.x; // 0..65535
    int lane = tid & 63;
    int s = (tid >> 6) & 3;
    int c = (tid >> 8) & 63;
    int wr = (tid >> 14) & 1;
    int l = tid >> 15;
    int q2 = lane >> 5;
    int n31 = lane & 31;
    const float* W = l ? W2 : W1;
    const float* base = W + (wr * 32 + n31) * 4096 + c * 64 + s * 16 + 8 * q2;
    float4 v0 = *(const float4*)base;
    float4 v1 = *(const float4*)(base + 4);
    u32x4 pv;
    pv[0] = pk2bf_rne(v0.x, v0.y);
    pv[1] = pk2bf_rne(v0.z, v0.w);
    pv[2] = pk2bf_rne(v1.x, v1.y);
    pv[3] = pk2bf_rne(v1.z, v1.w);
    ((u32x4*)Wp)[tid] = pv;
}

// Block = 2 batches, 4 waves: wave w -> (bl = w>>1, wr = w&1); each wave owns
// C-tile [32 o x 64 d] (2 n-tiles, 2 accs). Grid 512 = 2 blocks/CU (LDS 74.8KB).
// Per K-chunk (KC=64): all 256 threads build y-tile (both batches) into
// double-buffered sY; waves run 8 MFMA from sY + asm A-ring (r6's verified
// depth-3 global ring, counted vmcnt(12)). In-loop barriers are RAW s_barrier
// + lgkmcnt(0) ONLY — no vmcnt drain, so A prefetches survive barriers.
__global__ __launch_bounds__(256, 2) void cin_kernel(const float* __restrict__ x,
                                                     const unsigned short* __restrict__ Wp,
                                                     const float* __restrict__ b1,
                                                     const float* __restrict__ b2,
                                                     const float* __restrict__ Wfc,
                                                     const float* __restrict__ bfc,
                                                     float* __restrict__ out) {
    // sH[bl][l][d*72 + f]: f = i (x) or j (h1), bf16, transposed, stride 72
    __shared__ __align__(16) unsigned short sH[2][2][64 * 72]; // 36.9 KB
    // sY[bl][buf][d*72 + k']: y-chunk, same layout as sH rows
    __shared__ __align__(16) unsigned short sY[2][2][64 * 72]; // 36.9 KB
    __shared__ float sBias[128], sWfc[128], sRed[4];

    const int tid = threadIdx.x;
    const int w = tid >> 6;
    const int lane = tid & 63;
    const int q2 = lane >> 5;
    const int n31 = lane & 31;
    const int bl = w >> 1;  // batch within block
    const int wr = w & 1;   // o-half
    const int bb = blockIdx.x;
    const char* WpB = (const char*)Wp;

    // ---- stage x for both batches: coalesced float4 -> transposed bf16 ----
#pragma unroll
    for (int b2i = 0; b2i < 2; ++b2i) {
        const float4* xb4 = (const float4*)(x + (bb * 2 + b2i) * 4096);
#pragma unroll
        for (int rr = 0; rr < 4; ++rr) {
            int e4 = rr * 256 + tid;
            float4 v = xb4[e4];
            int e = e4 << 2;
            int f = e >> 6;
            int d0 = e & 63;
            sH[b2i][0][(d0 + 0) * 72 + f] = f2bf(v.x);
            sH[b2i][0][(d0 + 1) * 72 + f] = f2bf(v.y);
            sH[b2i][0][(d0 + 2) * 72 + f] = f2bf(v.z);
            sH[b2i][0][(d0 + 3) * 72 + f] = f2bf(v.w);
        }
    }
    if (tid < 128) {
        sBias[tid] = (tid < 64) ? b1[tid] : b2[tid - 64];
        sWfc[tid] = Wfc[tid];
    }
    __syncthreads(); // full drain: vmcnt==0 from here; only A-ring loads follow

    const f32x16 zz = {};
    float contrib = 0.0f;

    // ---- A ring: 4 slots x 4 frags (asm-loaded, 64 VGPR) ----
    s16x8 Ar[4][4];
#pragma unroll
    for (int g0 = 0; g0 < 3; ++g0) { // groups 0,1,2 (l=0, c=0..2) -> slots 0..2
        const char* gp = WpB + (size_t)((wr * 64 + g0) * 4096) + lane * 16;
        GLOADX4(Ar[g0][0], gp, "0");
        GLOADX4(Ar[g0][1], gp, "1024");
        GLOADX4(Ar[g0][2], gp, "2048");
        GLOADX4(Ar[g0][3], gp, "3072");
    }
    __builtin_amdgcn_sched_barrier(0);

    // ---- y-tile fill: thread covers (blf, dd, 32 k's); 4 VALU/pair ----
    auto FILL = [&](int l_, int c_, int nb) {
        const int blf = tid >> 7;
        const int dd = (tid >> 1) & 63;
        const int k0 = (tid & 1) << 5;
        const unsigned short* hs = &sH[blf][l_][dd * 72];
        const float xf = bf2f(sH[blf][0][dd * 72 + c_]); // x[i=c_, d]
        const f32x2 xf2 = {xf, xf};
        unsigned short* yd = &sY[blf][nb][dd * 72 + k0];
#pragma unroll
        for (int p = 0; p < 4; ++p) {
            s16x8 h8 = *(const s16x8*)&hs[k0 + p * 8];
            u32x4 o4;
#pragma unroll
            for (int q = 0; q < 4; ++q) {
                f32x2 hp = {bf2f((unsigned short)h8[2 * q]),
                            bf2f((unsigned short)h8[2 * q + 1])};
                f32x2 pr = hp * xf2; // v_pk_mul_f32
                asm("v_cvt_pk_bf16_f32 %0, %1, %2"
                    : "=v"(o4[q]) : "v"(pr.x), "v"(pr.y));
            }
            *(u32x4*)&yd[p * 8] = o4;
        }
    };

// One K-chunk: B-reads (BUF) -> A-prefetch g+3 -> counted vmcnt -> 8 MFMA
// -> fill next chunk (NBUF) -> lgkm + raw barrier. Slot S literal.
#define CHUNK(C, S, BUF, NBUF)                                                    \
    {                                                                             \
        const int c_ = (C);                                                       \
        const int g = l * 64 + c_;                                                \
        s16x8 Bf[4][2];                                                           \
        _Pragma("unroll") for (int s = 0; s < 4; ++s)                             \
            _Pragma("unroll") for (int nt = 0; nt < 2; ++nt)                      \
                Bf[s][nt] = *(const s16x8*)&sY[bl][BUF]                           \
                    [(nt * 32 + n31) * 72 + s * 16 + 8 * q2];                     \
        if (g < 125) {                                                            \
            const int gn = g + 3;                                                 \
            const char* gp = WpB +                                                \
                (size_t)(((((gn >> 6) * 2 + wr) * 64 + (gn & 63)) * 4096)) +      \
                lane * 16;                                                        \
            GLOADX4(Ar[((S) + 3) & 3][0], gp, "0");                               \
            GLOADX4(Ar[((S) + 3) & 3][1], gp, "1024");                            \
            GLOADX4(Ar[((S) + 3) & 3][2], gp, "2048");                            \
            GLOADX4(Ar[((S) + 3) & 3][3], gp, "3072");                            \
        }                                                                         \
        __builtin_amdgcn_sched_barrier(0);                                        \
        if (g < 125) {                                                            \
            asm volatile("s_waitcnt vmcnt(12)" ::: "memory");                     \
        } else if (g == 125) {                                                    \
            asm volatile("s_waitcnt vmcnt(8)" ::: "memory");                      \
        } else if (g == 126) {                                                    \
            asm volatile("s_waitcnt vmcnt(4)" ::: "memory");                      \
        } else {                                                                  \
            asm volatile("s_waitcnt vmcnt(0)" ::: "memory");                      \
        }                                                                         \
        __builtin_amdgcn_sched_barrier(0);                                        \
        _Pragma("unroll") for (int s = 0; s < 4; ++s) {                           \
            acc0 = __builtin_amdgcn_mfma_f32_32x32x16_bf16(Ar[S][s], Bf[s][0],    \
                                                           acc0, 0, 0, 0);        \
            acc1 = __builtin_amdgcn_mfma_f32_32x32x16_bf16(Ar[S][s], Bf[s][1],    \
                                                           acc1, 0, 0, 0);        \
        }                                                                         \
        if (c_ < 63) FILL(l, c_ + 1, NBUF);                                       \
        asm volatile("s_waitcnt lgkmcnt(0)" ::: "memory");                        \
        __builtin_amdgcn_s_barrier();                                             \
        __builtin_amdgcn_sched_barrier(0);                                        \
    }

    for (int l = 0; l < 2; ++l) {
        f32x16 acc0 = zz, acc1 = zz;

        // pre-layer: fill chunk 0 into buf 0 (raw barrier: A-ring stays in flight)
        FILL(l, 0, 0);
        asm volatile("s_waitcnt lgkmcnt(0)" ::: "memory");
        __builtin_amdgcn_s_barrier();
        __builtin_amdgcn_sched_barrier(0);

        for (int cb = 0; cb < 64; cb += 4) {
            CHUNK(cb + 0, 0, 0, 1);
            CHUNK(cb + 1, 1, 1, 0);
            CHUNK(cb + 2, 2, 0, 1);
            CHUNK(cb + 3, 3, 1, 0);
        }

        // ---- layer epilogue: bias + relu + fc-contrib (+ h1 handoff) ----
#pragma unroll
        for (int nt = 0; nt < 2; ++nt) {
            const int d = nt * 32 + n31;
#pragma unroll
            for (int r = 0; r < 16; ++r) {
                const int o = wr * 32 + (r & 3) + 8 * (r >> 2) + 4 * q2;
                float av = nt ? acc1[r] : acc0[r];
                float v = fmaxf(av + sBias[l * 64 + o], 0.0f);
                contrib += v * sWfc[l * 64 + o];
                if (l == 0) sH[bl][1][d * 72 + o] = f2bf(v);
            }
        }
        if (l == 0) { // h1 visible to all waves before layer-1 fill
            asm volatile("s_waitcnt lgkmcnt(0)" ::: "memory");
            __builtin_amdgcn_s_barrier();
            __builtin_amdgcn_sched_barrier(0);
        }
    }
#undef CHUNK

    // ---- reduce: each (o,d) counted exactly once (C-tiles partition) ----
#pragma unroll
    for (int off = 32; off > 0; off >>= 1)
        contrib += __shfl_down(contrib, off, 64);
    if (lane == 0) sRed[w] = contrib;
    __syncthreads();
    if (tid < 2)
        out[bb * 2 + tid] = sRed[tid * 2] + sRed[tid * 2 + 1] + bfc[0];
}

extern "C" void kernel_launch(void* const* d_in, const int* in_sizes, int n_in,
                              void* d_out, int out_size, void* d_ws, size_t ws_size,
                              hipStream_t stream) {
    const float* x = (const float*)d_in[0];
    const float* W1 = (const float*)d_in[1];
    const float* b1 = (const float*)d_in[2];
    const float* W2 = (const float*)d_in[3];
    const float* b2 = (const float*)d_in[4];
    const float* Wfc = (const float*)d_in[5];
    const float* bfc = (const float*)d_in[6];
    float* out = (float*)d_out;

    unsigned short* Wp = (unsigned short*)d_ws; // 1 MB prepacked W (GEMM layout)

    prepack_kernel<<<256, 256, 0, stream>>>(W1, W2, Wp);
    cin_kernel<<<512, 256, 0, stream>>>(x, Wp, b1, b2, Wfc, bfc, out);
}